// Round 15
// baseline (22347.902 us; speedup 1.0000x reference)
//
#include <hip/hip_runtime.h>
#include <stdint.h>
#include <stddef.h>

typedef __bf16 bf16x8 __attribute__((ext_vector_type(8)));
typedef float f32x4 __attribute__((ext_vector_type(4)));

#define MFMA16(a, b, c) __builtin_amdgcn_mfma_f32_16x16x32_bf16((a), (b), (c), 0, 0, 0)

// problem dims
#define TSTEPS 1024
#define NDIM   64
#define NKC    10     // K = 320: 0..63 noise | 64..319 h  (x-cols handled in VALU)
#define NGT    64
#define MB     16
#define GROUPS 32
#define SLICES 8

// workspace layout (bytes)
#define GOFF    ((size_t)0)
#define GBYTES  ((size_t)NGT * NKC * 1024)       // 655360
#define W1OFF   (GOFF + GBYTES)
#define W1BYTES ((size_t)16 * 8 * 1024)          // 131072
#define BOFF    (W1OFF + W1BYTES)                // 1024 f32 reordered gate bias
#define XOFF    (BOFF + 4096)                    // mailbox: 256 slices * 2 parity * 512 u32
#define XBYTES  ((size_t)256 * 2 * 512 * 4)      // 1 MiB
#define WSNEED  (XOFF + XBYTES)

__device__ __forceinline__ uint16_t f2bf(float f) {
    union { float f; uint32_t u; } v; v.f = f;
    return (uint16_t)((v.u + 0x7FFFu + ((v.u >> 16) & 1u)) >> 16);  // RNE
}
__device__ __forceinline__ float fsig(float x) { return 1.0f / (1.0f + __expf(-x)); }
__device__ __forceinline__ float ftanh(float x) { return 2.0f / (1.0f + __expf(-2.0f * x)) - 1.0f; }

// lgkmcnt-only barrier: does NOT drain vmcnt
__device__ __forceinline__ void bar_lgkm() {
    asm volatile("s_waitcnt lgkmcnt(0)" ::: "memory");
    __builtin_amdgcn_s_barrier();
    asm volatile("" ::: "memory");
}

// ---- prep: gate weights [1024 x 320] bf16, rows interleaved rho = 4*unit + gate
__global__ void prep_gates(const float* __restrict__ W_ih, const float* __restrict__ W_hh,
                           char* __restrict__ ws) {
    int F = blockIdx.x;
    int T = F / NKC, kc = F - T * NKC;
    int l = threadIdx.x;
    int row  = 16 * T + (l & 15);
    int unit = row >> 2, gt = row & 3;
    int orig = gt * 256 + unit;              // torch gate order i,f,g,o blocks of 256
    uint32_t w[4];
#pragma unroll
    for (int p = 0; p < 4; ++p) {
        float v[2];
#pragma unroll
        for (int e = 0; e < 2; ++e) {
            int k = 32 * kc + 8 * (l >> 4) + 2 * p + e;
            v[e] = (k < 64) ? W_ih[orig * 67 + 3 + k] : W_hh[orig * 256 + (k - 64)];
        }
        w[p] = (uint32_t)f2bf(v[0]) | ((uint32_t)f2bf(v[1]) << 16);
    }
    *(uint4*)(ws + GOFF + (size_t)F * 1024 + (size_t)l * 16) = make_uint4(w[0], w[1], w[2], w[3]);
}

// ---- prep: W1 [256 x 256] bf16, frag-major
__global__ void prep_w1(const float* __restrict__ W1, char* __restrict__ ws) {
    int F = blockIdx.x;
    int T = F / 8, kc = F - T * 8;
    int l = threadIdx.x;
    int row = 16 * T + (l & 15);
    uint32_t w[4];
#pragma unroll
    for (int p = 0; p < 4; ++p) {
        int k = 32 * kc + 8 * (l >> 4) + 2 * p;
        w[p] = (uint32_t)f2bf(W1[row * 256 + k]) | ((uint32_t)f2bf(W1[row * 256 + k + 1]) << 16);
    }
    *(uint4*)(ws + W1OFF + (size_t)F * 1024 + (size_t)l * 16) = make_uint4(w[0], w[1], w[2], w[3]);
}

// ---- prep: reordered gate bias
__global__ void prep_small(const float* __restrict__ b_ih, const float* __restrict__ b_hh,
                           char* __restrict__ ws) {
    int t = threadIdx.x;
    float* sb = (float*)(ws + BOFF);
    if (t < 1024) {
        int unit = t >> 2, gt = t & 3;
        int orig = gt * 256 + unit;
        sb[t] = b_ih[orig] + b_hh[orig];
    }
}

// ---- main: 256 blocks (32 groups x 8 slices), R9 structure with coherence-forced
//      transport: publish = atomic swap (executes AT the coherent point, no
//      writer-L2 write-back laziness); poll = buffer_inv sc1 per sweep (drops
//      stale non-local L2 lines so every sweep's loads read the coherent point).
__global__ __launch_bounds__(512, 2) void lstm_main(
        const float* __restrict__ noise, const float* __restrict__ gap,
        const float* __restrict__ W_ih, const float* __restrict__ b1p,
        const float* __restrict__ W2p, const float* __restrict__ b2p,
        char* __restrict__ ws, float* __restrict__ out) {
    __shared__ uint16_t act[MB * 320];   // [batch][k], XOR-swizzled, bf16; h at 64..319
    __shared__ float dp_part[16][9];     // padded: conflict-free
    __shared__ float gxy[2][16][2];      // parity-doubled gap staging

    const int tid  = threadIdx.x;
    const int w    = tid >> 6;
    const int lane = tid & 63;
    const int q    = lane >> 4;
    const int col  = lane & 15;
    const int g    = blockIdx.x >> 3;
    const int s    = blockIdx.x & 7;
    const int b0   = g * MB;
    const int swz  = (col & 7) << 3;

    const uint4* gfr  = (const uint4*)(ws + GOFF);
    const uint4* w1fr = (const uint4*)(ws + W1OFF);
    const float* bias = (const float*)(ws + BOFF);
    uint32_t* pay = (uint32_t*)(ws + XOFF);

    for (int i = tid; i < MB * 320; i += 512) act[i] = 0;

    // ---- weights -> VGPRs
    const int T = 8 * s + w;             // this wave's gate row-tile (global)
    uint4 gw[NKC];
#pragma unroll
    for (int kc = 0; kc < NKC; ++kc) gw[kc] = gfr[(size_t)(T * NKC + kc) * 64 + lane];
    uint4 w1w[16];                        // full W1: wave w holds head row-tiles 2w, 2w+1
#pragma unroll
    for (int i = 0; i < 2; ++i)
#pragma unroll
        for (int kc = 0; kc < 8; ++kc)
            w1w[i * 8 + kc] = w1fr[(size_t)((2 * w + i) * 8 + kc) * 64 + lane];

    const int rb = 16 * T + 4 * q;
    const float bI = bias[rb], bF = bias[rb + 1], bG = bias[rb + 2], bO = bias[rb + 3];
    float wx0[4], wx1[4], wx2[4];        // f32 x-column weights (rank-3 VALU path)
#pragma unroll
    for (int r = 0; r < 4; ++r) {
        int row = rb + r;
        int orig = (row & 3) * 256 + (row >> 2);
        wx0[r] = W_ih[orig * 67 + 0];
        wx1[r] = W_ih[orig * 67 + 1];
        wx2[r] = W_ih[orig * 67 + 2] * 24.0f;
    }
    float b1r[8], w2r[8];
#pragma unroll
    for (int a = 0; a < 2; ++a)
#pragma unroll
        for (int r = 0; r < 4; ++r) {
            int row = 32 * w + 16 * a + 4 * q + r;
            b1r[4 * a + r] = b1p[row];
            w2r[4 * a + r] = W2p[row];
        }
    const float b2v = b2p[0];

    // ---- prefetch t=0
    const int nbr = tid >> 5, nj = (tid & 31) * 2;
    const float* nptr = noise + (size_t)(b0 + nbr) * TSTEPS * NDIM + nj;
    float2 npf = *(const float2*)nptr;
    const bool xlead = (w == 7 && lane < 16);
    const bool olead = (s == 0 && w == 0);
    float2 gpf = make_float2(0.f, 0.f);
    if (xlead) gpf = *(const float2*)(gap + (size_t)(b0 + col) * (TSTEPS + 1) * 2);

    float creg = 0.f;
    float o_g0 = 0.f, o_g1 = 0.f, o_tdp = 0.f;   // deferred out payload (step t-1)
    const f32x4 fz = {0.f, 0.f, 0.f, 0.f};
    const int myidx = g * 8 + s;
    const int myunit = 32 * s + 4 * w + q;

    __syncthreads();

#pragma unroll 1
    for (int t = 0; t <= TSTEPS; ++t) {
        const int par = t & 1;
        const uint32_t tg = (uint32_t)t;

        // ---- Phase A: stage noise + gxy; poll 7 peers (inv-refreshed); deferred out
        if (t < TSTEPS) {
            uint32_t nv = (uint32_t)f2bf(npf.x) | ((uint32_t)f2bf(npf.y) << 16);
            int sw = (nbr & 7) << 3;
            *(uint32_t*)&act[nbr * 320 + (nj ^ sw)] = nv;
        }
        if (xlead) { gxy[par][col][0] = gpf.x; gxy[par][col][1] = gpf.y; }

        if (t > 0) {   // receive 7 peer h-slices: tag match == data valid
            unsigned pend = 0x7f;
            uint32_t vv[7];
            // drop stale non-local L2 lines so this sweep reads the coherent point
            asm volatile("buffer_inv sc1" ::: "memory");
            do {
#pragma unroll
                for (int pi = 0; pi < 7; ++pi)
                    if (pend & (1u << pi)) {
                        int p = (s + 1 + pi) & 7;
                        vv[pi] = __hip_atomic_load(
                            &pay[(((g * 8 + p) * 2 + par) << 9) + 64 * w + lane],
                            __ATOMIC_RELAXED, __HIP_MEMORY_SCOPE_AGENT);
                    }
#pragma unroll
                for (int pi = 0; pi < 7; ++pi)
                    if ((pend & (1u << pi)) && (vv[pi] >> 16) == tg) {
                        int p = (s + 1 + pi) & 7;
                        int u = 32 * p + 4 * w + q;
                        act[col * 320 + ((64 + u) ^ swz)] = (uint16_t)vv[pi];
                        pend &= ~(1u << pi);
                    }
                if (pend)   // refresh before the next sweep
                    asm volatile("s_waitcnt vmcnt(0)\n\tbuffer_inv sc1" ::: "memory");
            } while (pend);
            // deferred out row (t-1): HBM stores drain during bar+B, not in the poll
            if (olead && q == 0) {
                float* o = out + ((size_t)(b0 + col) * (TSTEPS + 1) + (t - 1)) * 3;
                o[0] = o_g0; o[1] = o_g1; o[2] = 24.0f * o_tdp;
            }
        }
        // prefetches AFTER the poll so the poll's waits never cover HBM loads
        if (t + 1 < TSTEPS) npf = *(const float2*)(nptr + (size_t)(t + 1) * NDIM);
        if (xlead && t < TSTEPS)
            gpf = *(const float2*)(gap + ((size_t)(b0 + col) * (TSTEPS + 1) + (t + 1)) * 2);
        bar_lgkm();

        // ---- Phase B: gates (noise+h) and head overlapped, shared LDS reads
        f32x4 h0 = fz, h1 = fz, ga = fz;
        {
            bf16x8 bn0 = *(const bf16x8*)&act[col * 320 + ((8 * q) ^ swz)];
            bf16x8 bn1 = *(const bf16x8*)&act[col * 320 + ((32 + 8 * q) ^ swz)];
            ga = MFMA16(__builtin_bit_cast(bf16x8, gw[0]), bn0, ga);
            ga = MFMA16(__builtin_bit_cast(bf16x8, gw[1]), bn1, ga);
        }
#pragma unroll
        for (int kc = 0; kc < 8; ++kc) {
            bf16x8 bv = *(const bf16x8*)&act[col * 320 + ((64 + 32 * kc + 8 * q) ^ swz)];
            ga = MFMA16(__builtin_bit_cast(bf16x8, gw[2 + kc]), bv, ga);
            h0 = MFMA16(__builtin_bit_cast(bf16x8, w1w[kc]),     bv, h0);
            h1 = MFMA16(__builtin_bit_cast(bf16x8, w1w[8 + kc]), bv, h1);
        }
        float part = 0.f;
#pragma unroll
        for (int r = 0; r < 4; ++r) {
            part += ftanh(h0[r] + b1r[r])     * w2r[r];
            part += ftanh(h1[r] + b1r[4 + r]) * w2r[4 + r];
        }
        part += __shfl_xor(part, 16);
        part += __shfl_xor(part, 32);
        if (q == 0) dp_part[col][w] = part;
        bar_lgkm();

        // ---- Phase C: dp finalize, elementwise, publish (LDS writes last)
        const float* dpp = &dp_part[col][0];
        float inner = b2v + ((dpp[0] + dpp[1]) + (dpp[2] + dpp[3]))
                          + ((dpp[4] + dpp[5]) + (dpp[6] + dpp[7]));
        float tdp = ftanh(inner);
        const float g0 = gxy[par][col][0], g1 = gxy[par][col][1];
        o_g0 = g0; o_g1 = g1; o_tdp = tdp;

        if (t == TSTEPS) {
            if (olead && q == 0) {   // final row: no next phase A, write now
                float* o = out + ((size_t)(b0 + col) * (TSTEPS + 1) + t) * 3;
                o[0] = g0; o[1] = g1; o[2] = 24.0f * tdp;
            }
            break;
        }

        float ii = ga[0] + bI + wx0[0] * g0 + wx1[0] * g1 + wx2[0] * tdp;
        float ff = ga[1] + bF + wx0[1] * g0 + wx1[1] * g1 + wx2[1] * tdp;
        float gg = ga[2] + bG + wx0[2] * g0 + wx1[2] * g1 + wx2[2] * tdp;
        float oo = ga[3] + bO + wx0[3] * g0 + wx1[3] * g1 + wx2[3] * tdp;
        float cn = fsig(ff) * creg + fsig(ii) * ftanh(gg);
        creg = cn;
        float hv = fsig(oo) * ftanh(cn);
        uint16_t hb = f2bf(hv);

        // publish via atomic swap: the RMW executes AT the coherent point --
        // immediately visible to peers, independent of local-L2 write-back timing.
        // Result discarded (no-return swap -> fire-and-forget).
        (void)__hip_atomic_exchange(
            &pay[((myidx * 2 + ((t + 1) & 1)) << 9) + 64 * w + lane],
            ((uint32_t)(t + 1) << 16) | (uint32_t)hb,
            __ATOMIC_RELAXED, __HIP_MEMORY_SCOPE_AGENT);
        act[col * 320 + ((64 + myunit) ^ swz)] = hb;
    }
}

extern "C" void kernel_launch(void* const* d_in, const int* in_sizes, int n_in,
                              void* d_out, int out_size, void* d_ws, size_t ws_size,
                              hipStream_t stream) {
    (void)in_sizes; (void)n_in; (void)out_size;
    if (ws_size < WSNEED) return;  // fail loudly (output stays poisoned)

    const float* noise = (const float*)d_in[0];
    const float* gap   = (const float*)d_in[1];
    const float* W_ih  = (const float*)d_in[2];
    const float* W_hh  = (const float*)d_in[3];
    const float* b_ih  = (const float*)d_in[4];
    const float* b_hh  = (const float*)d_in[5];
    const float* W1    = (const float*)d_in[6];
    const float* b1    = (const float*)d_in[7];
    const float* W2    = (const float*)d_in[8];
    const float* b2    = (const float*)d_in[9];
    char*  ws  = (char*)d_ws;
    float* out = (float*)d_out;

    hipMemsetAsync(ws + XOFF, 0, XBYTES, stream);   // mailbox tags -> 0 (replay-safe)
    hipLaunchKernelGGL(prep_gates, dim3(NGT * NKC), dim3(64), 0, stream, W_ih, W_hh, ws);
    hipLaunchKernelGGL(prep_w1,    dim3(16 * 8),    dim3(64), 0, stream, W1, ws);
    hipLaunchKernelGGL(prep_small, dim3(1), dim3(1024), 0, stream, b_ih, b_hh, ws);
    hipLaunchKernelGGL(lstm_main,  dim3(GROUPS * SLICES), dim3(512), 0, stream,
                       noise, gap, W_ih, b1, W2, b2, ws, out);
}

// Round 16
// 3025.917 us; speedup vs baseline: 7.3855x; 7.3855x over previous
//
#include <hip/hip_runtime.h>
#include <stdint.h>
#include <stddef.h>

typedef __bf16 bf16x8 __attribute__((ext_vector_type(8)));
typedef float f32x4 __attribute__((ext_vector_type(4)));

#define MFMA16(a, b, c) __builtin_amdgcn_mfma_f32_16x16x32_bf16((a), (b), (c), 0, 0, 0)

// problem dims
#define TSTEPS 1024
#define NDIM   64
#define NKC    10     // K = 320: 0..63 noise | 64..319 h  (x-cols handled in VALU)
#define NGT    64
#define MB     16
#define GROUPS 32
#define SLICES 8

// workspace layout (bytes)
#define GOFF    ((size_t)0)
#define GBYTES  ((size_t)NGT * NKC * 1024)       // 655360
#define W1OFF   (GOFF + GBYTES)
#define W1BYTES ((size_t)16 * 8 * 1024)          // 131072
#define BOFF    (W1OFF + W1BYTES)                // 1024 f32 reordered gate bias
#define XOFF    (BOFF + 4096)                    // ids (1KB) | payF (1MB, sc0) | payS (1MB, agent)
#define IDSB    ((size_t)1024)
#define PAYB    ((size_t)256 * 2 * 512 * 4)      // 1 MiB per flavor
#define WSNEED  (XOFF + IDSB + 2 * PAYB)

__device__ __forceinline__ uint16_t f2bf(float f) {
    union { float f; uint32_t u; } v; v.f = f;
    return (uint16_t)((v.u + 0x7FFFu + ((v.u >> 16) & 1u)) >> 16);  // RNE
}
__device__ __forceinline__ float fsig(float x) { return 1.0f / (1.0f + __expf(-x)); }
__device__ __forceinline__ float ftanh(float x) { return 2.0f / (1.0f + __expf(-2.0f * x)) - 1.0f; }

// lgkmcnt-only barrier: does NOT drain vmcnt
__device__ __forceinline__ void bar_lgkm() {
    asm volatile("s_waitcnt lgkmcnt(0)" ::: "memory");
    __builtin_amdgcn_s_barrier();
    asm volatile("" ::: "memory");
}

// 7 sc0 (L1-bypass -> read the shared per-XCD L2, the intra-XCD coherence point)
// dword loads + single drain. Valid transport ONLY when writer is on the same XCD.
#define FPOLL7(R0, R1, R2, R3, R4, R5, R6, O0, O1, O2, O3, O4, O5, O6, SB)   \
    asm volatile(                                                            \
        "global_load_dword %0, %7, %14 sc0\n\t"                              \
        "global_load_dword %1, %8, %14 sc0\n\t"                              \
        "global_load_dword %2, %9, %14 sc0\n\t"                              \
        "global_load_dword %3, %10, %14 sc0\n\t"                             \
        "global_load_dword %4, %11, %14 sc0\n\t"                             \
        "global_load_dword %5, %12, %14 sc0\n\t"                             \
        "global_load_dword %6, %13, %14 sc0\n\t"                             \
        "s_waitcnt vmcnt(0)"                                                 \
        : "=&v"(R0), "=&v"(R1), "=&v"(R2), "=&v"(R3),                        \
          "=&v"(R4), "=&v"(R5), "=&v"(R6)                                    \
        : "v"(O0), "v"(O1), "v"(O2), "v"(O3), "v"(O4), "v"(O5), "v"(O6),     \
          "s"(SB)                                                            \
        : "memory")

// ---- prep: gate weights [1024 x 320] bf16, rows interleaved rho = 4*unit + gate
__global__ void prep_gates(const float* __restrict__ W_ih, const float* __restrict__ W_hh,
                           char* __restrict__ ws) {
    int F = blockIdx.x;
    int T = F / NKC, kc = F - T * NKC;
    int l = threadIdx.x;
    int row  = 16 * T + (l & 15);
    int unit = row >> 2, gt = row & 3;
    int orig = gt * 256 + unit;              // torch gate order i,f,g,o blocks of 256
    uint32_t w[4];
#pragma unroll
    for (int p = 0; p < 4; ++p) {
        float v[2];
#pragma unroll
        for (int e = 0; e < 2; ++e) {
            int k = 32 * kc + 8 * (l >> 4) + 2 * p + e;
            v[e] = (k < 64) ? W_ih[orig * 67 + 3 + k] : W_hh[orig * 256 + (k - 64)];
        }
        w[p] = (uint32_t)f2bf(v[0]) | ((uint32_t)f2bf(v[1]) << 16);
    }
    *(uint4*)(ws + GOFF + (size_t)F * 1024 + (size_t)l * 16) = make_uint4(w[0], w[1], w[2], w[3]);
}

// ---- prep: W1 [256 x 256] bf16, frag-major
__global__ void prep_w1(const float* __restrict__ W1, char* __restrict__ ws) {
    int F = blockIdx.x;
    int T = F / 8, kc = F - T * 8;
    int l = threadIdx.x;
    int row = 16 * T + (l & 15);
    uint32_t w[4];
#pragma unroll
    for (int p = 0; p < 4; ++p) {
        int k = 32 * kc + 8 * (l >> 4) + 2 * p;
        w[p] = (uint32_t)f2bf(W1[row * 256 + k]) | ((uint32_t)f2bf(W1[row * 256 + k + 1]) << 16);
    }
    *(uint4*)(ws + W1OFF + (size_t)F * 1024 + (size_t)l * 16) = make_uint4(w[0], w[1], w[2], w[3]);
}

// ---- prep: reordered gate bias
__global__ void prep_small(const float* __restrict__ b_ih, const float* __restrict__ b_hh,
                           char* __restrict__ ws) {
    int t = threadIdx.x;
    float* sb = (float*)(ws + BOFF);
    if (t < 1024) {
        int unit = t >> 2, gt = t & 3;
        int orig = gt * 256 + unit;
        sb[t] = b_ih[orig] + b_hh[orig];
    }
}

// ---- main: 256 blocks; RUNTIME XCD discovery -> same-XCD groups of 8 use the
//      shared per-XCD L2 (sc0 store + sc0 poll, ~300cy RT); leftover/mixed groups
//      use the proven agent/MALL path. Dual publish + proof-based watchdog.
__global__ __launch_bounds__(512, 2) void lstm_main(
        const float* __restrict__ noise, const float* __restrict__ gap,
        const float* __restrict__ W_ih, const float* __restrict__ b1p,
        const float* __restrict__ W2p, const float* __restrict__ b2p,
        char* __restrict__ ws, float* __restrict__ out) {
    __shared__ uint16_t act[MB * 320];   // [batch][k], XOR-swizzled, bf16; h at 64..319
    __shared__ float dp_part[16][9];
    __shared__ float gxy[2][16][2];
    __shared__ uint32_t sIds[256];

    const int tid  = threadIdx.x;
    const int w    = tid >> 6;
    const int lane = tid & 63;
    const int q    = lane >> 4;
    const int col  = lane & 15;
    const int swz  = (col & 7) << 3;

    const uint4* gfr  = (const uint4*)(ws + GOFF);
    const uint4* w1fr = (const uint4*)(ws + W1OFF);
    const float* bias = (const float*)(ws + BOFF);
    uint32_t* ids = (uint32_t*)(ws + XOFF);
    const uint64_t payF_base = (uint64_t)(uintptr_t)(ws + XOFF + IDSB);
    uint32_t* payS = (uint32_t*)(ws + XOFF + IDSB + PAYB);

    for (int i = tid; i < MB * 320; i += 512) act[i] = 0;

    // ---- runtime placement discovery (agent path, one-time, all 256 co-resident)
    uint32_t myx;
    asm volatile("s_getreg_b32 %0, hwreg(HW_REG_XCC_ID)" : "=s"(myx));
    myx &= 0xffu;
    if (tid == 0)
        __hip_atomic_store(&ids[blockIdx.x], 0x100u | myx,
                           __ATOMIC_RELAXED, __HIP_MEMORY_SCOPE_AGENT);
    if (tid < 256) {
        uint32_t v;
        do { v = __hip_atomic_load(&ids[tid], __ATOMIC_RELAXED,
                                   __HIP_MEMORY_SCOPE_AGENT); } while (!(v & 0x100u));
        sIds[tid] = v & 0xffu;
    }
    __syncthreads();

    // deterministic role assignment (every thread computes identically)
    const int myblk = blockIdx.x;
    int cnt[8] = {0, 0, 0, 0, 0, 0, 0, 0};
    int r = 0;
    for (int j = 0; j < 256; ++j) {
        int x = (int)sIds[j];
        if (j < myblk && x == (int)myx) ++r;
        ++cnt[x & 7];
    }
    int base = 0, NF = 0, Lpre = 0;
    for (int x = 0; x < 8; ++x) {
        int nf = cnt[x] >> 3;
        if (x < (int)myx) { base += nf; Lpre += cnt[x] & 7; }
        NF += nf;
    }
    const int nfm = cnt[myx & 7] >> 3;
    int g, s; bool fast;
    if (r < 8 * nfm) { g = base + (r >> 3); s = r & 7; fast = true; }
    else { int L = Lpre + (r - 8 * nfm); g = NF + (L >> 3); s = L & 7; fast = false; }
    const int b0 = g * MB;
    const int myidx = g * 8 + s;
    const int myunit = 32 * s + 4 * w + q;

    // ---- weights -> VGPRs (roles now known)
    const int T = 8 * s + w;
    uint4 gw[NKC];
#pragma unroll
    for (int kc = 0; kc < NKC; ++kc) gw[kc] = gfr[(size_t)(T * NKC + kc) * 64 + lane];
    uint4 w1w[16];
#pragma unroll
    for (int i = 0; i < 2; ++i)
#pragma unroll
        for (int kc = 0; kc < 8; ++kc)
            w1w[i * 8 + kc] = w1fr[(size_t)((2 * w + i) * 8 + kc) * 64 + lane];

    const int rb = 16 * T + 4 * q;
    const float bI = bias[rb], bF = bias[rb + 1], bG = bias[rb + 2], bO = bias[rb + 3];
    float wx0[4], wx1[4], wx2[4];
#pragma unroll
    for (int rr = 0; rr < 4; ++rr) {
        int row = rb + rr;
        int orig = (row & 3) * 256 + (row >> 2);
        wx0[rr] = W_ih[orig * 67 + 0];
        wx1[rr] = W_ih[orig * 67 + 1];
        wx2[rr] = W_ih[orig * 67 + 2] * 24.0f;
    }
    float b1r[8], w2r[8];
#pragma unroll
    for (int a = 0; a < 2; ++a)
#pragma unroll
        for (int rr = 0; rr < 4; ++rr) {
            int row = 32 * w + 16 * a + 4 * q + rr;
            b1r[4 * a + rr] = b1p[row];
            w2r[4 * a + rr] = W2p[row];
        }
    const float b2v = b2p[0];

    // ---- mailbox addressing
    uint32_t vof[7];
#pragma unroll
    for (int pi = 0; pi < 7; ++pi) {
        int p = (s + 1 + pi) & 7;
        vof[pi] = ((uint32_t)(g * 8 + p) << 12) + (uint32_t)((64 * w + lane) * 4);
    }
    const uint32_t myvof = ((uint32_t)myidx << 12) + (uint32_t)((64 * w + lane) * 4);

    // ---- prefetch t=0
    const int nbr = tid >> 5, nj = (tid & 31) * 2;
    const float* nptr = noise + (size_t)(b0 + nbr) * TSTEPS * NDIM + nj;
    float2 npf = *(const float2*)nptr;
    const bool xlead = (w == 7 && lane < 16);
    const bool olead = (s == 0 && w == 0);
    float2 gpf = make_float2(0.f, 0.f);
    if (xlead) gpf = *(const float2*)(gap + (size_t)(b0 + col) * (TSTEPS + 1) * 2);

    float creg = 0.f;
    float o_g0 = 0.f, o_g1 = 0.f, o_tdp = 0.f;
    const f32x4 fz = {0.f, 0.f, 0.f, 0.f};
    int fmMiss = 0;
    bool fm = fast;

    __syncthreads();

#pragma unroll 1
    for (int t = 0; t <= TSTEPS; ++t) {
        const int par = t & 1;
        const uint32_t tg = (uint32_t)t;

        // ---- Phase A: stage noise + gxy; poll 7 peers; deferred out; prefetch
        if (t < TSTEPS) {
            uint32_t nv = (uint32_t)f2bf(npf.x) | ((uint32_t)f2bf(npf.y) << 16);
            int sw = (nbr & 7) << 3;
            *(uint32_t*)&act[nbr * 320 + (nj ^ sw)] = nv;
        }
        if (xlead) { gxy[par][col][0] = gpf.x; gxy[par][col][1] = gpf.y; }

        if (t > 0) {
            unsigned pend = 0x7f;
            if (fm) {   // intra-XCD L2 transport: sc0 sweeps, fresh every sweep
                const uint32_t parb = (uint32_t)(par << 11);
                uint32_t o0 = vof[0] + parb, o1 = vof[1] + parb, o2 = vof[2] + parb,
                         o3 = vof[3] + parb, o4 = vof[4] + parb, o5 = vof[5] + parb,
                         o6 = vof[6] + parb;
                int spins = 0;
                for (;;) {
                    uint32_t r0, r1, r2, r3, r4, r5, r6;
                    FPOLL7(r0, r1, r2, r3, r4, r5, r6, o0, o1, o2, o3, o4, o5, o6,
                           payF_base);
                    uint32_t rr[7] = {r0, r1, r2, r3, r4, r5, r6};
#pragma unroll
                    for (int pi = 0; pi < 7; ++pi)
                        if ((pend & (1u << pi)) && (rr[pi] >> 16) == tg) {
                            int p = (s + 1 + pi) & 7;
                            int u = 32 * p + 4 * w + q;
                            act[col * 320 + ((64 + u) ^ swz)] = (uint16_t)rr[pi];
                            pend &= ~(1u << pi);
                        }
                    if (!pend) break;
                    // proof-based watchdog: if the agent copy has the tag but the
                    // sc0 view doesn't, the fast mechanism is broken -> count miss
                    if ((++spins & 127) == 127) {
                        uint32_t vv[7];
#pragma unroll
                        for (int pi = 0; pi < 7; ++pi)
                            if (pend & (1u << pi)) {
                                int p = (s + 1 + pi) & 7;
                                vv[pi] = __hip_atomic_load(
                                    &payS[(((g * 8 + p) * 2 + par) << 9) + 64 * w + lane],
                                    __ATOMIC_RELAXED, __HIP_MEMORY_SCOPE_AGENT);
                            }
#pragma unroll
                        for (int pi = 0; pi < 7; ++pi)
                            if ((pend & (1u << pi)) && (vv[pi] >> 16) == tg) {
                                int p = (s + 1 + pi) & 7;
                                int u = 32 * p + 4 * w + q;
                                act[col * 320 + ((64 + u) ^ swz)] = (uint16_t)vv[pi];
                                pend &= ~(1u << pi);
                            }
                        if (!pend) { ++fmMiss; break; }
                    }
                }
                if (fmMiss >= 4) fm = false;   // mechanism proven broken -> latch
            }
            if (pend) {   // proven agent/MALL fallback (R9)
                uint32_t vv[7];
                do {
#pragma unroll
                    for (int pi = 0; pi < 7; ++pi)
                        if (pend & (1u << pi)) {
                            int p = (s + 1 + pi) & 7;
                            vv[pi] = __hip_atomic_load(
                                &payS[(((g * 8 + p) * 2 + par) << 9) + 64 * w + lane],
                                __ATOMIC_RELAXED, __HIP_MEMORY_SCOPE_AGENT);
                        }
#pragma unroll
                    for (int pi = 0; pi < 7; ++pi)
                        if ((pend & (1u << pi)) && (vv[pi] >> 16) == tg) {
                            int p = (s + 1 + pi) & 7;
                            int u = 32 * p + 4 * w + q;
                            act[col * 320 + ((64 + u) ^ swz)] = (uint16_t)vv[pi];
                            pend &= ~(1u << pi);
                        }
                } while (pend);
            }
            fm = __all(fm);
            if (olead && q == 0) {
                float* o = out + ((size_t)(b0 + col) * (TSTEPS + 1) + (t - 1)) * 3;
                o[0] = o_g0; o[1] = o_g1; o[2] = 24.0f * o_tdp;
            }
        }
        if (t + 1 < TSTEPS) npf = *(const float2*)(nptr + (size_t)(t + 1) * NDIM);
        if (xlead && t < TSTEPS)
            gpf = *(const float2*)(gap + ((size_t)(b0 + col) * (TSTEPS + 1) + (t + 1)) * 2);
        bar_lgkm();

        // ---- Phase B: gates (noise+h) and head overlapped, shared LDS reads
        f32x4 h0 = fz, h1 = fz, ga = fz;
        {
            bf16x8 bn0 = *(const bf16x8*)&act[col * 320 + ((8 * q) ^ swz)];
            bf16x8 bn1 = *(const bf16x8*)&act[col * 320 + ((32 + 8 * q) ^ swz)];
            ga = MFMA16(__builtin_bit_cast(bf16x8, gw[0]), bn0, ga);
            ga = MFMA16(__builtin_bit_cast(bf16x8, gw[1]), bn1, ga);
        }
#pragma unroll
        for (int kc = 0; kc < 8; ++kc) {
            bf16x8 bv = *(const bf16x8*)&act[col * 320 + ((64 + 32 * kc + 8 * q) ^ swz)];
            ga = MFMA16(__builtin_bit_cast(bf16x8, gw[2 + kc]), bv, ga);
            h0 = MFMA16(__builtin_bit_cast(bf16x8, w1w[kc]),     bv, h0);
            h1 = MFMA16(__builtin_bit_cast(bf16x8, w1w[8 + kc]), bv, h1);
        }
        float part = 0.f;
#pragma unroll
        for (int rr = 0; rr < 4; ++rr) {
            part += ftanh(h0[rr] + b1r[rr])     * w2r[rr];
            part += ftanh(h1[rr] + b1r[4 + rr]) * w2r[4 + rr];
        }
        part += __shfl_xor(part, 16);
        part += __shfl_xor(part, 32);
        if (q == 0) dp_part[col][w] = part;
        bar_lgkm();

        // ---- Phase C: dp finalize, elementwise, publish (dual), LDS last
        const float* dpp = &dp_part[col][0];
        float inner = b2v + ((dpp[0] + dpp[1]) + (dpp[2] + dpp[3]))
                          + ((dpp[4] + dpp[5]) + (dpp[6] + dpp[7]));
        float tdp = ftanh(inner);
        const float g0 = gxy[par][col][0], g1 = gxy[par][col][1];
        o_g0 = g0; o_g1 = g1; o_tdp = tdp;

        if (t == TSTEPS) {
            if (olead && q == 0) {
                float* o = out + ((size_t)(b0 + col) * (TSTEPS + 1) + t) * 3;
                o[0] = g0; o[1] = g1; o[2] = 24.0f * tdp;
            }
            break;
        }

        float ii = ga[0] + bI + wx0[0] * g0 + wx1[0] * g1 + wx2[0] * tdp;
        float ff = ga[1] + bF + wx0[1] * g0 + wx1[1] * g1 + wx2[1] * tdp;
        float gg = ga[2] + bG + wx0[2] * g0 + wx1[2] * g1 + wx2[2] * tdp;
        float oo = ga[3] + bO + wx0[3] * g0 + wx1[3] * g1 + wx2[3] * tdp;
        float cn = fsig(ff) * creg + fsig(ii) * ftanh(gg);
        creg = cn;
        float hv = fsig(oo) * ftanh(cn);
        uint16_t hb = f2bf(hv);

        // dual publish: sc0 -> shared XCD L2 (fast readers); agent -> MALL (fallback)
        uint32_t word = ((uint32_t)(t + 1) << 16) | (uint32_t)hb;
        uint32_t wvo = myvof + (uint32_t)(((t + 1) & 1) << 11);
        asm volatile("global_store_dword %0, %1, %2 sc0"
                     :: "v"(wvo), "v"(word), "s"(payF_base) : "memory");
        __hip_atomic_store(&payS[((myidx * 2 + ((t + 1) & 1)) << 9) + 64 * w + lane],
                           word, __ATOMIC_RELAXED, __HIP_MEMORY_SCOPE_AGENT);
        act[col * 320 + ((64 + myunit) ^ swz)] = hb;
    }
}

extern "C" void kernel_launch(void* const* d_in, const int* in_sizes, int n_in,
                              void* d_out, int out_size, void* d_ws, size_t ws_size,
                              hipStream_t stream) {
    (void)in_sizes; (void)n_in; (void)out_size;
    if (ws_size < WSNEED) return;  // fail loudly (output stays poisoned)

    const float* noise = (const float*)d_in[0];
    const float* gap   = (const float*)d_in[1];
    const float* W_ih  = (const float*)d_in[2];
    const float* W_hh  = (const float*)d_in[3];
    const float* b_ih  = (const float*)d_in[4];
    const float* b_hh  = (const float*)d_in[5];
    const float* W1    = (const float*)d_in[6];
    const float* b1    = (const float*)d_in[7];
    const float* W2    = (const float*)d_in[8];
    const float* b2    = (const float*)d_in[9];
    char*  ws  = (char*)d_ws;
    float* out = (float*)d_out;

    hipMemsetAsync(ws + XOFF, 0, IDSB + 2 * PAYB, stream);  // ids + both mailboxes
    hipLaunchKernelGGL(prep_gates, dim3(NGT * NKC), dim3(64), 0, stream, W_ih, W_hh, ws);
    hipLaunchKernelGGL(prep_w1,    dim3(16 * 8),    dim3(64), 0, stream, W1, ws);
    hipLaunchKernelGGL(prep_small, dim3(1), dim3(1024), 0, stream, b_ih, b_hh, ws);
    hipLaunchKernelGGL(lstm_main,  dim3(256), dim3(512), 0, stream,
                       noise, gap, W_ih, b1, W2, b2, ws, out);
}